// Round 1
// baseline (4563.294 us; speedup 1.0000x reference)
//
#include <hip/hip_runtime.h>
#include <math.h>

#define LANES 64

static __device__ __forceinline__ float leaky(float v) {
    return v >= 0.f ? v : 0.2f * v;
}

// ---------------------------------------------------------------------------
// Kernel 1: per-node GEMVs: Ux = x@U^T+Ub, Vx = x@V^T+Vb, Ax = x@A^T+Ab, Bx = x@B^T+Bb
// one wave per node, lane = output feature d
// ---------------------------------------------------------------------------
__global__ void node_gemm(const float* __restrict__ x,
                          const float* __restrict__ Uw, const float* __restrict__ Ub,
                          const float* __restrict__ Vw, const float* __restrict__ Vb,
                          const float* __restrict__ Aw, const float* __restrict__ Ab,
                          const float* __restrict__ Bw, const float* __restrict__ Bb,
                          float* __restrict__ Ux, float* __restrict__ Vx,
                          float* __restrict__ Ax, float* __restrict__ Bx, int n)
{
    int wave = (blockIdx.x * blockDim.x + threadIdx.x) >> 6;
    int lane = threadIdx.x & 63;
    if (wave >= n) return;
    float xv = x[wave * LANES + lane];
    float au = Ub[lane], av = Vb[lane], aa = Ab[lane], ab = Bb[lane];
    const float* uR = Uw + lane * LANES;
    const float* vR = Vw + lane * LANES;
    const float* aR = Aw + lane * LANES;
    const float* bR = Bw + lane * LANES;
#pragma unroll 8
    for (int k = 0; k < 64; ++k) {
        float xk = __shfl(xv, k, 64);
        au += xk * uR[k];
        av += xk * vR[k];
        aa += xk * aR[k];
        ab += xk * bR[k];
    }
    int o = wave * LANES + lane;
    Ux[o] = au; Vx[o] = av; Ax[o] = aa; Bx[o] = ab;
}

// ---------------------------------------------------------------------------
// CSR build: histogram of src, exclusive scan (1 block), scatter edge ids
// ---------------------------------------------------------------------------
__global__ void hist_kernel(const int* __restrict__ src, int* __restrict__ deg, int e)
{
    int i = blockIdx.x * blockDim.x + threadIdx.x;
    if (i < e) atomicAdd(&deg[src[i]], 1);
}

__global__ void scan_kernel(const int* __restrict__ deg,
                            int* __restrict__ row_start,
                            int* __restrict__ cursor, int n)
{
    __shared__ int sdata[1024];
    int t = threadIdx.x;
    int chunk = (n + 1023) >> 10;
    int start = t * chunk;
    int end = min(start + chunk, n);
    int s = 0;
    for (int i = start; i < end; ++i) s += deg[i];
    sdata[t] = s;
    __syncthreads();
    // Hillis-Steele inclusive scan
    for (int ofs = 1; ofs < 1024; ofs <<= 1) {
        int v = (t >= ofs) ? sdata[t - ofs] : 0;
        __syncthreads();
        sdata[t] += v;
        __syncthreads();
    }
    int run = sdata[t] - s;   // exclusive prefix for this thread's chunk
    for (int i = start; i < end; ++i) {
        row_start[i] = run;
        cursor[i] = run;
        run += deg[i];
    }
    if (start < n && n <= start + chunk) row_start[n] = run;
}

__global__ void fill_kernel(const int* __restrict__ src, int* __restrict__ cursor,
                            int* __restrict__ csr, int e)
{
    int i = blockIdx.x * blockDim.x + threadIdx.x;
    if (i < e) {
        int s = src[i];
        int p = atomicAdd(&cursor[s], 1);
        csr[p] = i;
    }
}

// ---------------------------------------------------------------------------
// Kernel: per-node online-softmax aggregation + x_new epilogue
// one wave per node, lane = feature d. Softmax is independent per (node, d).
// ---------------------------------------------------------------------------
__global__ void node_agg(const float* __restrict__ x, const float* __restrict__ ehat,
                         const int* __restrict__ dst,
                         const int* __restrict__ row_start, const int* __restrict__ csr,
                         const float* __restrict__ Ux, const float* __restrict__ Vx,
                         float* __restrict__ xnew, int n)
{
    int wave = (blockIdx.x * blockDim.x + threadIdx.x) >> 6;
    int lane = threadIdx.x & 63;
    if (wave >= n) return;
    int beg = row_start[wave];
    int end = row_start[wave + 1];
    float m = -INFINITY, s = 0.f, y = 0.f;
    for (int p = beg; p < end; ++p) {
        int eid = csr[p];
        float v = ehat[(size_t)eid * LANES + lane];
        int dn = dst[eid];
        float vx = Vx[(size_t)dn * LANES + lane];
        float mn = fmaxf(m, v);
        float c = __expf(m - mn);   // first iter: exp(-inf)=0
        float pw = __expf(v - mn);
        s = s * c + pw;
        y = y * c + pw * vx;
        m = mn;
    }
    float agg = (s > 0.f) ? y / s : 0.f;
    int o = wave * LANES + lane;
    float pre = Ux[o] + agg;
    xnew[o] = x[o] + leaky(pre);
}

// ---------------------------------------------------------------------------
// Kernel: per-edge e_new = e_hat + leaky(Ax[src] + Bx[dst] + e_hat@C^T + Cb)
// one wave per edge, lane = output feature; C GEMV via shuffle broadcast
// ---------------------------------------------------------------------------
__global__ void edge_new(const float* __restrict__ ehat,
                         const int* __restrict__ src, const int* __restrict__ dst,
                         const float* __restrict__ Ax, const float* __restrict__ Bx,
                         const float* __restrict__ Cw, const float* __restrict__ Cb,
                         float* __restrict__ enew, int e)
{
    int wave = (blockIdx.x * blockDim.x + threadIdx.x) >> 6;
    int lane = threadIdx.x & 63;
    if (wave >= e) return;
    size_t base = (size_t)wave * LANES;
    float v = ehat[base + lane];
    float acc = Cb[lane];
    const float* cR = Cw + lane * LANES;
#pragma unroll 8
    for (int k = 0; k < 64; ++k) {
        float ek = __shfl(v, k, 64);
        acc += ek * cR[k];
    }
    int sn = src[wave], dn = dst[wave];
    float t = acc + Ax[sn * LANES + lane] + Bx[dn * LANES + lane];
    enew[base + lane] = v + leaky(t);
}

// ---------------------------------------------------------------------------
extern "C" void kernel_launch(void* const* d_in, const int* in_sizes, int n_in,
                              void* d_out, int out_size, void* d_ws, size_t ws_size,
                              hipStream_t stream)
{
    const float* x    = (const float*)d_in[0];
    const float* ehat = (const float*)d_in[1];
    const int*   ei   = (const int*)d_in[2];
    const float* Uw = (const float*)d_in[3];
    const float* Ub = (const float*)d_in[4];
    const float* Vw = (const float*)d_in[5];
    const float* Vb = (const float*)d_in[6];
    const float* Aw = (const float*)d_in[7];
    const float* Ab = (const float*)d_in[8];
    const float* Bw = (const float*)d_in[9];
    const float* Bb = (const float*)d_in[10];
    const float* Cw = (const float*)d_in[11];
    const float* Cb = (const float*)d_in[12];

    int n = in_sizes[0] / LANES;   // 100000
    int e = in_sizes[1] / LANES;   // 1600000
    const int* src = ei;
    const int* dst = ei + e;

    // workspace carve (256B aligned)
    auto align = [](size_t v) { return (v + 255) & ~(size_t)255; };
    char* w = (char*)d_ws;
    int* deg      = (int*)w; w += align((size_t)n * 4);
    int* cursor   = (int*)w; w += align((size_t)n * 4);
    int* rs       = (int*)w; w += align((size_t)(n + 1) * 4);
    int* csr      = (int*)w; w += align((size_t)e * 4);
    float* Ux     = (float*)w; w += align((size_t)n * LANES * 4);
    float* Vx     = (float*)w; w += align((size_t)n * LANES * 4);
    float* Ax     = (float*)w; w += align((size_t)n * LANES * 4);
    float* Bx     = (float*)w; w += align((size_t)n * LANES * 4);

    float* xnew = (float*)d_out;
    float* enew = xnew + (size_t)n * LANES;

    hipMemsetAsync(deg, 0, (size_t)n * 4, stream);

    // per-node linear layers (4 tables)
    {
        int waves_per_block = 4;              // 256 threads
        int blocks = (n + waves_per_block - 1) / waves_per_block;
        node_gemm<<<blocks, 256, 0, stream>>>(x, Uw, Ub, Vw, Vb, Aw, Ab, Bw, Bb,
                                              Ux, Vx, Ax, Bx, n);
    }

    // CSR by src
    hist_kernel<<<(e + 255) / 256, 256, 0, stream>>>(src, deg, e);
    scan_kernel<<<1, 1024, 0, stream>>>(deg, rs, cursor, n);
    fill_kernel<<<(e + 255) / 256, 256, 0, stream>>>(src, cursor, csr, e);

    // node aggregation (online softmax) + x_new
    node_agg<<<(n + 3) / 4, 256, 0, stream>>>(x, ehat, dst, rs, csr, Ux, Vx, xnew, n);

    // e_new
    edge_new<<<(e + 3) / 4, 256, 0, stream>>>(ehat, src, dst, Ax, Bx, Cw, Cb, enew, e);
}

// Round 2
// 1115.289 us; speedup vs baseline: 4.0916x; 4.0916x over previous
//
#include <hip/hip_runtime.h>
#include <math.h>
#include <stdint.h>

#define LANES 64

typedef __attribute__((ext_vector_type(8))) short bf16x8;
typedef __attribute__((ext_vector_type(4))) float f32x4;

static __device__ __forceinline__ float leaky(float v) {
    return v >= 0.f ? v : 0.2f * v;
}

// float -> bf16 (RNE) as raw short
static __device__ __forceinline__ short f2bf(float f) {
    uint32_t u = __float_as_uint(f);
    u = (u + 0x7FFFu + ((u >> 16) & 1u)) >> 16;
    return (short)u;
}

// ---------------------------------------------------------------------------
// MFMA helper: load B-fragments for a 64x64 weight W (row-major, out_row x k)
// computing T = A @ W^T. B[k][col] = W[col][k].
// lane l, col-tile ct, k-step s: holds W[16*ct + (l&15)][32*s + 8*(l>>4) + j]
// ---------------------------------------------------------------------------
static __device__ __forceinline__ void load_bfrags(const float* __restrict__ W,
                                                   int lo, int hi, bf16x8 bf[4][2]) {
#pragma unroll
    for (int ct = 0; ct < 4; ++ct) {
        const float* cp = W + (size_t)(ct * 16 + lo) * 64 + hi * 8;
#pragma unroll
        for (int s = 0; s < 2; ++s) {
            float4 c0 = *(const float4*)(cp + 32 * s);
            float4 c1 = *(const float4*)(cp + 32 * s + 4);
            bf16x8 b;
            b[0] = f2bf(c0.x); b[1] = f2bf(c0.y); b[2] = f2bf(c0.z); b[3] = f2bf(c0.w);
            b[4] = f2bf(c1.x); b[5] = f2bf(c1.y); b[6] = f2bf(c1.z); b[7] = f2bf(c1.w);
            bf[ct][s] = b;
        }
    }
}

// ---------------------------------------------------------------------------
// Kernel 1 (MFMA): per-node tables Ux,Vx,Ax,Bx = x@W^T + b for W in {U,V,A,B}
// block = 256 thr = 4 waves; block handles 16 nodes; wave w computes matrix w.
// ---------------------------------------------------------------------------
__global__ void node_gemm_mfma(const float* __restrict__ x,
                               const float* __restrict__ Uw, const float* __restrict__ Ub,
                               const float* __restrict__ Vw, const float* __restrict__ Vb,
                               const float* __restrict__ Aw, const float* __restrict__ Ab,
                               const float* __restrict__ Bw, const float* __restrict__ Bb,
                               float* __restrict__ Ux, float* __restrict__ Vx,
                               float* __restrict__ Ax, float* __restrict__ Bx, int n)
{
    __shared__ float tile[16][68];
    int t = threadIdx.x;
    int w = t >> 6;
    int l = t & 63;
    int lo = l & 15, hi = l >> 4;
    long base = (long)blockIdx.x * 16;
    if (base >= n) return;

    // cooperative x-tile load: thread t -> row t>>4, cols (t&15)*4..+3
    {
        int row = t >> 4, c4 = (t & 15) * 4;
        float4 v = *(const float4*)(x + (base + row) * 64 + c4);
        *(float4*)&tile[row][c4] = v;
    }

    const float* Wp = (w == 0) ? Uw : (w == 1) ? Vw : (w == 2) ? Aw : Bw;
    const float* bp = (w == 0) ? Ub : (w == 1) ? Vb : (w == 2) ? Ab : Bb;
    float*       op = (w == 0) ? Ux : (w == 1) ? Vx : (w == 2) ? Ax : Bx;

    bf16x8 bf[4][2];
    load_bfrags(Wp, lo, hi, bf);
    __syncthreads();

    // A-frags from LDS: lane l -> row lo, k = 32*s + 8*hi + j
    bf16x8 a[2];
#pragma unroll
    for (int s = 0; s < 2; ++s) {
        float4 a0 = *(const float4*)&tile[lo][s * 32 + hi * 8];
        float4 a1 = *(const float4*)&tile[lo][s * 32 + hi * 8 + 4];
        bf16x8 av;
        av[0] = f2bf(a0.x); av[1] = f2bf(a0.y); av[2] = f2bf(a0.z); av[3] = f2bf(a0.w);
        av[4] = f2bf(a1.x); av[5] = f2bf(a1.y); av[6] = f2bf(a1.z); av[7] = f2bf(a1.w);
        a[s] = av;
    }

    f32x4 acc[4];
#pragma unroll
    for (int ct = 0; ct < 4; ++ct) {
        acc[ct] = (f32x4){0.f, 0.f, 0.f, 0.f};
        acc[ct] = __builtin_amdgcn_mfma_f32_16x16x32_bf16(a[0], bf[ct][0], acc[ct], 0, 0, 0);
        acc[ct] = __builtin_amdgcn_mfma_f32_16x16x32_bf16(a[1], bf[ct][1], acc[ct], 0, 0, 0);
    }

    // epilogue: D[row=(hi*4+i)][col=16ct+lo] + bias
#pragma unroll
    for (int i = 0; i < 4; ++i) {
        long nd = base + hi * 4 + i;
#pragma unroll
        for (int ct = 0; ct < 4; ++ct) {
            int col = ct * 16 + lo;
            op[nd * 64 + col] = acc[ct][i] + bp[col];
        }
    }
}

// ---------------------------------------------------------------------------
// CSR build: histogram of src, exclusive scan (1 block), scatter edge ids
// ---------------------------------------------------------------------------
__global__ void hist_kernel(const int* __restrict__ src, int* __restrict__ deg, int e)
{
    int i = blockIdx.x * blockDim.x + threadIdx.x;
    if (i < e) atomicAdd(&deg[src[i]], 1);
}

__global__ void scan_kernel(const int* __restrict__ deg,
                            int* __restrict__ row_start,
                            int* __restrict__ cursor, int n)
{
    __shared__ int sdata[1024];
    int t = threadIdx.x;
    int chunk = (n + 1023) >> 10;
    int start = t * chunk;
    int end = min(start + chunk, n);
    int s = 0;
    for (int i = start; i < end; ++i) s += deg[i];
    sdata[t] = s;
    __syncthreads();
    for (int ofs = 1; ofs < 1024; ofs <<= 1) {
        int v = (t >= ofs) ? sdata[t - ofs] : 0;
        __syncthreads();
        sdata[t] += v;
        __syncthreads();
    }
    int run = sdata[t] - s;
    for (int i = start; i < end; ++i) {
        row_start[i] = run;
        cursor[i] = run;
        run += deg[i];
    }
    if (start < n && n <= start + chunk) row_start[n] = run;
}

__global__ void fill_kernel(const int* __restrict__ src, int* __restrict__ cursor,
                            int* __restrict__ csr, int e)
{
    int i = blockIdx.x * blockDim.x + threadIdx.x;
    if (i < e) {
        int s = src[i];
        int p = atomicAdd(&cursor[s], 1);
        csr[p] = i;
    }
}

// ---------------------------------------------------------------------------
// per-node online-softmax aggregation + x_new epilogue (one wave per node)
// ---------------------------------------------------------------------------
__global__ void node_agg(const float* __restrict__ x, const float* __restrict__ ehat,
                         const int* __restrict__ dst,
                         const int* __restrict__ row_start, const int* __restrict__ csr,
                         const float* __restrict__ Ux, const float* __restrict__ Vx,
                         float* __restrict__ xnew, int n)
{
    int wave = (blockIdx.x * blockDim.x + threadIdx.x) >> 6;
    int lane = threadIdx.x & 63;
    if (wave >= n) return;
    int beg = row_start[wave];
    int end = row_start[wave + 1];
    float m = -INFINITY, s = 0.f, y = 0.f;
    for (int p = beg; p < end; ++p) {
        int eid = csr[p];
        float v = ehat[(size_t)eid * LANES + lane];
        int dn = dst[eid];
        float vx = Vx[(size_t)dn * LANES + lane];
        float mn = fmaxf(m, v);
        float c = __expf(m - mn);
        float pw = __expf(v - mn);
        s = s * c + pw;
        y = y * c + pw * vx;
        m = mn;
    }
    float agg = (s > 0.f) ? y / s : 0.f;
    int o = wave * LANES + lane;
    float pre = Ux[o] + agg;
    xnew[o] = x[o] + leaky(pre);
}

// ---------------------------------------------------------------------------
// Kernel (MFMA): e_new = e_hat + leaky(Ax[src] + Bx[dst] + e_hat@C^T + Cb)
// block = 256 thr = 4 waves; each wave owns 16 edges (tile 16x64).
// ---------------------------------------------------------------------------
__global__ void edge_new_mfma(const float* __restrict__ ehat,
                              const int* __restrict__ src, const int* __restrict__ dst,
                              const float* __restrict__ Ax, const float* __restrict__ Bx,
                              const float* __restrict__ Cw, const float* __restrict__ Cb,
                              float* __restrict__ enew, int e)
{
    __shared__ float tile[4][16][68];
    int w = threadIdx.x >> 6;
    int l = threadIdx.x & 63;
    int lo = l & 15, hi = l >> 4;
    long base = ((long)blockIdx.x * 4 + w) * 16;
    if (base >= e) return;

    // B-frags for C (kept in regs for the whole wave)
    bf16x8 bf[4][2];
    load_bfrags(Cw, lo, hi, bf);

    // stage 16x64 fp32 e_hat tile in LDS: it-loop, lane l -> row it*4+hi, cols lo*4..+3
#pragma unroll
    for (int it = 0; it < 4; ++it) {
        int row = it * 4 + hi;
        float4 v = *(const float4*)(ehat + (base + row) * 64 + lo * 4);
        *(float4*)&tile[w][row][lo * 4] = v;
    }
    __syncthreads();

    // A-frags: lane l -> row lo, k = 32*s + 8*hi + j
    bf16x8 a[2];
#pragma unroll
    for (int s = 0; s < 2; ++s) {
        float4 a0 = *(const float4*)&tile[w][lo][s * 32 + hi * 8];
        float4 a1 = *(const float4*)&tile[w][lo][s * 32 + hi * 8 + 4];
        bf16x8 av;
        av[0] = f2bf(a0.x); av[1] = f2bf(a0.y); av[2] = f2bf(a0.z); av[3] = f2bf(a0.w);
        av[4] = f2bf(a1.x); av[5] = f2bf(a1.y); av[6] = f2bf(a1.z); av[7] = f2bf(a1.w);
        a[s] = av;
    }

    f32x4 acc[4];
#pragma unroll
    for (int ct = 0; ct < 4; ++ct) {
        acc[ct] = (f32x4){0.f, 0.f, 0.f, 0.f};
        acc[ct] = __builtin_amdgcn_mfma_f32_16x16x32_bf16(a[0], bf[ct][0], acc[ct], 0, 0, 0);
        acc[ct] = __builtin_amdgcn_mfma_f32_16x16x32_bf16(a[1], bf[ct][1], acc[ct], 0, 0, 0);
    }

    // epilogue: D[row=hi*4+i][col=16ct+lo]
#pragma unroll
    for (int i = 0; i < 4; ++i) {
        long er = base + hi * 4 + i;
        int sn = src[er];
        int dn = dst[er];
#pragma unroll
        for (int ct = 0; ct < 4; ++ct) {
            int col = ct * 16 + lo;
            float tval = acc[ct][i] + Ax[(size_t)sn * 64 + col]
                                    + Bx[(size_t)dn * 64 + col] + Cb[col];
            float v = tile[w][hi * 4 + i][col];
            enew[(size_t)er * 64 + col] = v + leaky(tval);
        }
    }
}

// ---------------------------------------------------------------------------
extern "C" void kernel_launch(void* const* d_in, const int* in_sizes, int n_in,
                              void* d_out, int out_size, void* d_ws, size_t ws_size,
                              hipStream_t stream)
{
    const float* x    = (const float*)d_in[0];
    const float* ehat = (const float*)d_in[1];
    const int*   ei   = (const int*)d_in[2];
    const float* Uw = (const float*)d_in[3];
    const float* Ub = (const float*)d_in[4];
    const float* Vw = (const float*)d_in[5];
    const float* Vb = (const float*)d_in[6];
    const float* Aw = (const float*)d_in[7];
    const float* Ab = (const float*)d_in[8];
    const float* Bw = (const float*)d_in[9];
    const float* Bb = (const float*)d_in[10];
    const float* Cw = (const float*)d_in[11];
    const float* Cb = (const float*)d_in[12];

    int n = in_sizes[0] / LANES;   // 100000
    int e = in_sizes[1] / LANES;   // 1600000
    const int* src = ei;
    const int* dst = ei + e;

    auto align = [](size_t v) { return (v + 255) & ~(size_t)255; };
    char* w = (char*)d_ws;
    int* deg      = (int*)w; w += align((size_t)n * 4);
    int* cursor   = (int*)w; w += align((size_t)n * 4);
    int* rs       = (int*)w; w += align((size_t)(n + 1) * 4);
    int* csr      = (int*)w; w += align((size_t)e * 4);
    float* Ux     = (float*)w; w += align((size_t)n * LANES * 4);
    float* Vx     = (float*)w; w += align((size_t)n * LANES * 4);
    float* Ax     = (float*)w; w += align((size_t)n * LANES * 4);
    float* Bx     = (float*)w; w += align((size_t)n * LANES * 4);

    float* xnew = (float*)d_out;
    float* enew = xnew + (size_t)n * LANES;

    hipMemsetAsync(deg, 0, (size_t)n * 4, stream);

    // per-node linear layers via MFMA (16 nodes/block, 4 waves = 4 matrices)
    node_gemm_mfma<<<(n + 15) / 16, 256, 0, stream>>>(x, Uw, Ub, Vw, Vb, Aw, Ab, Bw, Bb,
                                                      Ux, Vx, Ax, Bx, n);

    // CSR by src
    hist_kernel<<<(e + 255) / 256, 256, 0, stream>>>(src, deg, e);
    scan_kernel<<<1, 1024, 0, stream>>>(deg, rs, cursor, n);
    fill_kernel<<<(e + 255) / 256, 256, 0, stream>>>(src, cursor, csr, e);

    // node aggregation (online softmax) + x_new
    node_agg<<<(n + 3) / 4, 256, 0, stream>>>(x, ehat, dst, rs, csr, Ux, Vx, xnew, n);

    // e_new via MFMA (64 edges/block)
    edge_new_mfma<<<(e + 63) / 64, 256, 0, stream>>>(ehat, src, dst, Ax, Bx, Cw, Cb, enew, e);
}

// Round 3
// 889.109 us; speedup vs baseline: 5.1324x; 1.2544x over previous
//
#include <hip/hip_runtime.h>
#include <math.h>
#include <stdint.h>

#define LANES 64

typedef __attribute__((ext_vector_type(8))) short bf16x8;
typedef __attribute__((ext_vector_type(4))) float f32x4;

static __device__ __forceinline__ float leaky(float v) {
    return v >= 0.f ? v : 0.2f * v;
}

// float -> bf16 (RNE) raw bits
static __device__ __forceinline__ short f2bf(float f) {
    uint32_t u = __float_as_uint(f);
    u = (u + 0x7FFFu + ((u >> 16) & 1u)) >> 16;
    return (short)u;
}

static __device__ __forceinline__ bf16x8 pack8(float4 a, float4 b) {
    bf16x8 r;
    r[0] = f2bf(a.x); r[1] = f2bf(a.y); r[2] = f2bf(a.z); r[3] = f2bf(a.w);
    r[4] = f2bf(b.x); r[5] = f2bf(b.y); r[6] = f2bf(b.z); r[7] = f2bf(b.w);
    return r;
}

// B-frags for 64x64 weight W (row-major out x k), computing A @ W^T.
// lane l, col-tile ct, k-step s holds W[16*ct + (l&15)][32*s + 8*(l>>4) + j]
static __device__ __forceinline__ void load_bfrags(const float* __restrict__ W,
                                                   int lo, int hi, bf16x8 bf[4][2]) {
#pragma unroll
    for (int ct = 0; ct < 4; ++ct) {
        const float* cp = W + (size_t)(ct * 16 + lo) * 64 + hi * 8;
#pragma unroll
        for (int s = 0; s < 2; ++s) {
            float4 c0 = *(const float4*)(cp + 32 * s);
            float4 c1 = *(const float4*)(cp + 32 * s + 4);
            bf[ct][s] = pack8(c0, c1);
        }
    }
}

// ---------------------------------------------------------------------------
// node tables: Ux,Vx,Ax,Bx = x@W^T + b. 64 nodes/block; wave w owns matrix w.
// ---------------------------------------------------------------------------
__global__ __launch_bounds__(256) void node_gemm_mfma(
        const float* __restrict__ x,
        const float* __restrict__ Uw, const float* __restrict__ Ub,
        const float* __restrict__ Vw, const float* __restrict__ Vb,
        const float* __restrict__ Aw, const float* __restrict__ Ab,
        const float* __restrict__ Bw, const float* __restrict__ Bb,
        float* __restrict__ Ux, float* __restrict__ Vx,
        float* __restrict__ Ax, float* __restrict__ Bx, int n)
{
    __shared__ float tile[64][68];
    int t = threadIdx.x;
    int w = t >> 6, l = t & 63;
    int lo = l & 15, hi = l >> 4;
    long base = (long)blockIdx.x * 64;

    // cooperative stage: thread t -> rows it*16 + (t>>4), cols (t&15)*4..+3
    int r16 = t >> 4, c4 = (t & 15) * 4;
#pragma unroll
    for (int it = 0; it < 4; ++it) {
        int row = it * 16 + r16;
        long nd = base + row;
        long ndc = nd < n ? nd : (long)n - 1;
        *(float4*)&tile[row][c4] = *(const float4*)(x + ndc * 64 + c4);
    }

    const float* Wp = (w == 0) ? Uw : (w == 1) ? Vw : (w == 2) ? Aw : Bw;
    const float* bp = (w == 0) ? Ub : (w == 1) ? Vb : (w == 2) ? Ab : Bb;
    float*       op = (w == 0) ? Ux : (w == 1) ? Vx : (w == 2) ? Ax : Bx;

    bf16x8 bf[4][2];
    load_bfrags(Wp, lo, hi, bf);
    __syncthreads();

#pragma unroll
    for (int st = 0; st < 4; ++st) {
        bf16x8 a[2];
#pragma unroll
        for (int s = 0; s < 2; ++s) {
            float4 a0 = *(const float4*)&tile[st * 16 + lo][s * 32 + hi * 8];
            float4 a1 = *(const float4*)&tile[st * 16 + lo][s * 32 + hi * 8 + 4];
            a[s] = pack8(a0, a1);
        }
#pragma unroll
        for (int ct = 0; ct < 4; ++ct) {
            f32x4 acc = (f32x4){0.f, 0.f, 0.f, 0.f};
            acc = __builtin_amdgcn_mfma_f32_16x16x32_bf16(a[0], bf[ct][0], acc, 0, 0, 0);
            acc = __builtin_amdgcn_mfma_f32_16x16x32_bf16(a[1], bf[ct][1], acc, 0, 0, 0);
            int col = ct * 16 + lo;
            float bias = bp[col];
#pragma unroll
            for (int i = 0; i < 4; ++i) {
                long nd = base + st * 16 + hi * 4 + i;
                if (nd < n) op[nd * 64 + col] = acc[i] + bias;
            }
        }
    }
}

// ---------------------------------------------------------------------------
// CSR build
// ---------------------------------------------------------------------------
__global__ void hist_kernel(const int* __restrict__ src, int* __restrict__ deg, int e)
{
    int i = blockIdx.x * blockDim.x + threadIdx.x;
    if (i < e) atomicAdd(&deg[src[i]], 1);
}

__global__ void scan_kernel(const int* __restrict__ deg,
                            int* __restrict__ row_start,
                            int* __restrict__ cursor, int n)
{
    __shared__ int sdata[1024];
    int t = threadIdx.x;
    int chunk = (n + 1023) >> 10;
    int start = t * chunk;
    int end = min(start + chunk, n);
    int s = 0;
    for (int i = start; i < end; ++i) s += deg[i];
    sdata[t] = s;
    __syncthreads();
    for (int ofs = 1; ofs < 1024; ofs <<= 1) {
        int v = (t >= ofs) ? sdata[t - ofs] : 0;
        __syncthreads();
        sdata[t] += v;
        __syncthreads();
    }
    int run = sdata[t] - s;
    for (int i = start; i < end; ++i) {
        row_start[i] = run;
        cursor[i] = run;
        run += deg[i];
    }
    if (start < n && n <= start + chunk) row_start[n] = run;
}

// stores (eid, dst[eid]) packed so node_agg reads one sequential array
__global__ void fill_kernel(const int* __restrict__ src, const int* __restrict__ dst,
                            int* __restrict__ cursor, int2* __restrict__ csr_ed, int e)
{
    int i = blockIdx.x * blockDim.x + threadIdx.x;
    if (i < e) {
        int s = src[i];
        int p = atomicAdd(&cursor[s], 1);
        csr_ed[p] = make_int2(i, dst[i]);
    }
}

// ---------------------------------------------------------------------------
// per-node online-softmax aggregation + x_new. Depth-8 software pipeline.
// ---------------------------------------------------------------------------
__global__ __launch_bounds__(256) void node_agg(
        const float* __restrict__ x, const float* __restrict__ ehat,
        const int* __restrict__ row_start, const int2* __restrict__ csr_ed,
        const float* __restrict__ Ux, const float* __restrict__ Vx,
        float* __restrict__ xnew, int n)
{
    int wid = (blockIdx.x * blockDim.x + threadIdx.x) >> 6;
    int lane = threadIdx.x & 63;
    if (wid >= n) return;
    int beg = row_start[wid];
    int end = row_start[wid + 1];
    float m = -INFINITY, s = 0.f, y = 0.f;

    int p = beg;
    while (p + 8 <= end) {
        int2 ed[8];
#pragma unroll
        for (int u = 0; u < 8; ++u) ed[u] = csr_ed[p + u];
        float v[8], vv[8];
#pragma unroll
        for (int u = 0; u < 8; ++u) {
            v[u]  = ehat[(size_t)ed[u].x * 64 + lane];
            vv[u] = Vx[(size_t)ed[u].y * 64 + lane];
        }
#pragma unroll
        for (int u = 0; u < 8; ++u) {
            float mn = fmaxf(m, v[u]);
            float c  = __expf(m - mn);
            float pw = __expf(v[u] - mn);
            s = s * c + pw;
            y = y * c + pw * vv[u];
            m = mn;
        }
        p += 8;
    }
    int cnt = end - p;   // 0..7 tail
    if (cnt > 0) {
        int2 ed[8];
        float v[8], vv[8];
#pragma unroll
        for (int u = 0; u < 8; ++u) {
            int q = p + (u < cnt ? u : 0);
            ed[u] = csr_ed[q];
        }
#pragma unroll
        for (int u = 0; u < 8; ++u) {
            v[u]  = ehat[(size_t)ed[u].x * 64 + lane];
            vv[u] = Vx[(size_t)ed[u].y * 64 + lane];
        }
#pragma unroll
        for (int u = 0; u < 8; ++u) {
            if (u < cnt) {
                float mn = fmaxf(m, v[u]);
                float c  = __expf(m - mn);
                float pw = __expf(v[u] - mn);
                s = s * c + pw;
                y = y * c + pw * vv[u];
                m = mn;
            }
        }
    }

    float agg = (s > 0.f) ? y / s : 0.f;
    int o = wid * LANES + lane;
    xnew[o] = x[o] + leaky(Ux[o] + agg);
}

// ---------------------------------------------------------------------------
// e_new = e_hat + leaky(Ax[src] + Bx[dst] + e_hat@C^T + Cb); 32 edges/wave
// ---------------------------------------------------------------------------
__global__ __launch_bounds__(256) void edge_new_mfma(
        const float* __restrict__ ehat,
        const int* __restrict__ src, const int* __restrict__ dst,
        const float* __restrict__ Ax, const float* __restrict__ Bx,
        const float* __restrict__ Cw, const float* __restrict__ Cb,
        float* __restrict__ enew, int e)
{
    __shared__ float tile[4][32][68];     // 34.8 KB, wave-private tiles
    int t = threadIdx.x;
    int w = t >> 6, l = t & 63;
    int lo = l & 15, hi = l >> 4;
    long base = ((long)blockIdx.x * 4 + w) * 32;

    bf16x8 bf[4][2];
    load_bfrags(Cw, lo, hi, bf);

    // stage 32x64 fp32 tile (wave-private; no barrier needed)
#pragma unroll
    for (int it = 0; it < 8; ++it) {
        int row = it * 4 + hi;
        long er = base + row;
        long erc = er < e ? er : (long)e - 1;
        *(float4*)&tile[w][row][lo * 4] = *(const float4*)(ehat + erc * 64 + lo * 4);
    }

#pragma unroll
    for (int st = 0; st < 2; ++st) {
        bf16x8 a[2];
#pragma unroll
        for (int s = 0; s < 2; ++s) {
            float4 a0 = *(const float4*)&tile[w][st * 16 + lo][s * 32 + hi * 8];
            float4 a1 = *(const float4*)&tile[w][st * 16 + lo][s * 32 + hi * 8 + 4];
            a[s] = pack8(a0, a1);
        }
        f32x4 acc[4];
#pragma unroll
        for (int ct = 0; ct < 4; ++ct) {
            acc[ct] = (f32x4){0.f, 0.f, 0.f, 0.f};
            acc[ct] = __builtin_amdgcn_mfma_f32_16x16x32_bf16(a[0], bf[ct][0], acc[ct], 0, 0, 0);
            acc[ct] = __builtin_amdgcn_mfma_f32_16x16x32_bf16(a[1], bf[ct][1], acc[ct], 0, 0, 0);
        }
#pragma unroll
        for (int i = 0; i < 4; ++i) {
            long er = base + st * 16 + hi * 4 + i;
            long erc = er < e ? er : (long)e - 1;
            int sn = src[erc];
            int dn = dst[erc];
#pragma unroll
            for (int ct = 0; ct < 4; ++ct) {
                int col = ct * 16 + lo;
                float tv = acc[ct][i] + Ax[(size_t)sn * 64 + col]
                                      + Bx[(size_t)dn * 64 + col] + Cb[col];
                float vv = tile[w][st * 16 + hi * 4 + i][col];
                if (er < e) enew[(size_t)er * 64 + col] = vv + leaky(tv);
            }
        }
    }
}

// ---------------------------------------------------------------------------
extern "C" void kernel_launch(void* const* d_in, const int* in_sizes, int n_in,
                              void* d_out, int out_size, void* d_ws, size_t ws_size,
                              hipStream_t stream)
{
    const float* x    = (const float*)d_in[0];
    const float* ehat = (const float*)d_in[1];
    const int*   ei   = (const int*)d_in[2];
    const float* Uw = (const float*)d_in[3];
    const float* Ub = (const float*)d_in[4];
    const float* Vw = (const float*)d_in[5];
    const float* Vb = (const float*)d_in[6];
    const float* Aw = (const float*)d_in[7];
    const float* Ab = (const float*)d_in[8];
    const float* Bw = (const float*)d_in[9];
    const float* Bb = (const float*)d_in[10];
    const float* Cw = (const float*)d_in[11];
    const float* Cb = (const float*)d_in[12];

    int n = in_sizes[0] / LANES;   // 100000
    int e = in_sizes[1] / LANES;   // 1600000
    const int* src = ei;
    const int* dst = ei + e;

    auto align = [](size_t v) { return (v + 255) & ~(size_t)255; };
    char* w = (char*)d_ws;
    int*  deg    = (int*)w;  w += align((size_t)n * 4);
    int*  cursor = (int*)w;  w += align((size_t)n * 4);
    int*  rs     = (int*)w;  w += align((size_t)(n + 1) * 4);
    int2* csr_ed = (int2*)w; w += align((size_t)e * 8);
    float* Ux    = (float*)w; w += align((size_t)n * LANES * 4);
    float* Vx    = (float*)w; w += align((size_t)n * LANES * 4);
    float* Ax    = (float*)w; w += align((size_t)n * LANES * 4);
    float* Bx    = (float*)w; w += align((size_t)n * LANES * 4);

    float* xnew = (float*)d_out;
    float* enew = xnew + (size_t)n * LANES;

    hipMemsetAsync(deg, 0, (size_t)n * 4, stream);

    node_gemm_mfma<<<(n + 63) / 64, 256, 0, stream>>>(x, Uw, Ub, Vw, Vb, Aw, Ab, Bw, Bb,
                                                      Ux, Vx, Ax, Bx, n);

    hist_kernel<<<(e + 255) / 256, 256, 0, stream>>>(src, deg, e);
    scan_kernel<<<1, 1024, 0, stream>>>(deg, rs, cursor, n);
    fill_kernel<<<(e + 255) / 256, 256, 0, stream>>>(src, dst, cursor, csr_ed, e);

    node_agg<<<(n + 3) / 4, 256, 0, stream>>>(x, ehat, rs, csr_ed, Ux, Vx, xnew, n);

    edge_new_mfma<<<(e + 127) / 128, 256, 0, stream>>>(ehat, src, dst, Ax, Bx, Cw, Cb, enew, e);
}

// Round 4
// 885.789 us; speedup vs baseline: 5.1517x; 1.0037x over previous
//
#include <hip/hip_runtime.h>
#include <math.h>
#include <stdint.h>

#define LANES 64

typedef __attribute__((ext_vector_type(8))) short bf16x8;
typedef __attribute__((ext_vector_type(4))) float f32x4;

static __device__ __forceinline__ float leaky(float v) {
    return v >= 0.f ? v : 0.2f * v;
}

// float -> bf16 (RNE) raw bits
static __device__ __forceinline__ short f2bf(float f) {
    uint32_t u = __float_as_uint(f);
    u = (u + 0x7FFFu + ((u >> 16) & 1u)) >> 16;
    return (short)u;
}

static __device__ __forceinline__ bf16x8 pack8(float4 a, float4 b) {
    bf16x8 r;
    r[0] = f2bf(a.x); r[1] = f2bf(a.y); r[2] = f2bf(a.z); r[3] = f2bf(a.w);
    r[4] = f2bf(b.x); r[5] = f2bf(b.y); r[6] = f2bf(b.z); r[7] = f2bf(b.w);
    return r;
}

static __device__ __forceinline__ float4 fuse4(float4 ev, float4 ac, float4 av,
                                               float4 bv, float4 cb) {
    float4 o;
    o.x = ev.x + leaky(ac.x + av.x + bv.x + cb.x);
    o.y = ev.y + leaky(ac.y + av.y + bv.y + cb.y);
    o.z = ev.z + leaky(ac.z + av.z + bv.z + cb.z);
    o.w = ev.w + leaky(ac.w + av.w + bv.w + cb.w);
    return o;
}

// B-frags from PRE-CONVERTED bf16 weight (row-major out x k): raw 16B loads.
// lane l, col-tile ct, k-step s holds W[16*ct + (l&15)][32*s + 8*(l>>4) + j]
static __device__ __forceinline__ void load_bfrags_bf16(const unsigned short* __restrict__ Wb,
                                                        int lo, int hi, bf16x8 bf[4][2]) {
#pragma unroll
    for (int ct = 0; ct < 4; ++ct)
#pragma unroll
        for (int s = 0; s < 2; ++s)
            bf[ct][s] = *(const bf16x8*)(Wb + (size_t)(ct * 16 + lo) * 64 + s * 32 + hi * 8);
}

// ---------------------------------------------------------------------------
// one-time weight conversion: 5 x 64x64 fp32 -> bf16 (U,V,A,B,C)
// ---------------------------------------------------------------------------
__global__ void cvt_weights(const float* __restrict__ U, const float* __restrict__ V,
                            const float* __restrict__ A, const float* __restrict__ B,
                            const float* __restrict__ C, unsigned short* __restrict__ out)
{
    int i = blockIdx.x * 256 + threadIdx.x;       // 0..20479
    int m = i >> 12, r = i & 4095;
    const float* p = (m == 0) ? U : (m == 1) ? V : (m == 2) ? A : (m == 3) ? B : C;
    out[i] = (unsigned short)f2bf(p[r]);
}

// ---------------------------------------------------------------------------
// node tables: Ux,Vx,Ax,Bx = x@W^T + b. 64 nodes/block; wave w owns matrix w.
// ---------------------------------------------------------------------------
__global__ __launch_bounds__(256) void node_gemm_mfma(
        const float* __restrict__ x, const unsigned short* __restrict__ Wbf,
        const float* __restrict__ Ub, const float* __restrict__ Vb,
        const float* __restrict__ Ab, const float* __restrict__ Bb,
        float* __restrict__ Ux, float* __restrict__ Vx,
        float* __restrict__ Ax, float* __restrict__ Bx, int n)
{
    __shared__ __align__(16) float tile[64][68];
    int t = threadIdx.x;
    int w = t >> 6, l = t & 63;
    int lo = l & 15, hi = l >> 4;
    long base = (long)blockIdx.x * 64;

    int r16 = t >> 4, c4 = (t & 15) * 4;
#pragma unroll
    for (int it = 0; it < 4; ++it) {
        int row = it * 16 + r16;
        long nd = base + row;
        long ndc = nd < n ? nd : (long)n - 1;
        *(float4*)&tile[row][c4] = *(const float4*)(x + ndc * 64 + c4);
    }

    const float* bp = (w == 0) ? Ub : (w == 1) ? Vb : (w == 2) ? Ab : Bb;
    float*       op = (w == 0) ? Ux : (w == 1) ? Vx : (w == 2) ? Ax : Bx;

    bf16x8 bf[4][2];
    load_bfrags_bf16(Wbf + (size_t)w * 4096, lo, hi, bf);
    __syncthreads();

#pragma unroll
    for (int st = 0; st < 4; ++st) {
        bf16x8 a[2];
#pragma unroll
        for (int s = 0; s < 2; ++s) {
            float4 a0 = *(const float4*)&tile[st * 16 + lo][s * 32 + hi * 8];
            float4 a1 = *(const float4*)&tile[st * 16 + lo][s * 32 + hi * 8 + 4];
            a[s] = pack8(a0, a1);
        }
#pragma unroll
        for (int ct = 0; ct < 4; ++ct) {
            f32x4 acc = (f32x4){0.f, 0.f, 0.f, 0.f};
            acc = __builtin_amdgcn_mfma_f32_16x16x32_bf16(a[0], bf[ct][0], acc, 0, 0, 0);
            acc = __builtin_amdgcn_mfma_f32_16x16x32_bf16(a[1], bf[ct][1], acc, 0, 0, 0);
            int col = ct * 16 + lo;
            float bias = bp[col];
#pragma unroll
            for (int i = 0; i < 4; ++i) {
                long nd = base + st * 16 + hi * 4 + i;
                if (nd < n) op[nd * 64 + col] = acc[i] + bias;
            }
        }
    }
}

// ---------------------------------------------------------------------------
// CSR build
// ---------------------------------------------------------------------------
__global__ void hist_kernel(const int* __restrict__ src, int* __restrict__ deg, int e)
{
    int i = blockIdx.x * blockDim.x + threadIdx.x;
    if (i < e) atomicAdd(&deg[src[i]], 1);
}

__global__ void scan_kernel(const int* __restrict__ deg,
                            int* __restrict__ row_start,
                            int* __restrict__ cursor, int n)
{
    __shared__ int sdata[1024];
    int t = threadIdx.x;
    int chunk = (n + 1023) >> 10;
    int start = t * chunk;
    int end = min(start + chunk, n);
    int s = 0;
    for (int i = start; i < end; ++i) s += deg[i];
    sdata[t] = s;
    __syncthreads();
    for (int ofs = 1; ofs < 1024; ofs <<= 1) {
        int v = (t >= ofs) ? sdata[t - ofs] : 0;
        __syncthreads();
        sdata[t] += v;
        __syncthreads();
    }
    int run = sdata[t] - s;
    for (int i = start; i < end; ++i) {
        row_start[i] = run;
        cursor[i] = run;
        run += deg[i];
    }
    if (start < n && n <= start + chunk) row_start[n] = run;
}

__global__ void fill_kernel(const int* __restrict__ src, const int* __restrict__ dst,
                            int* __restrict__ cursor, int2* __restrict__ csr_ed, int e)
{
    int i = blockIdx.x * blockDim.x + threadIdx.x;
    if (i < e) {
        int s = src[i];
        int p = atomicAdd(&cursor[s], 1);
        csr_ed[p] = make_int2(i, dst[i]);
    }
}

// ---------------------------------------------------------------------------
// per-node online-softmax aggregation + x_new. Depth-8 software pipeline.
// ---------------------------------------------------------------------------
__global__ __launch_bounds__(256) void node_agg(
        const float* __restrict__ x, const float* __restrict__ ehat,
        const int* __restrict__ row_start, const int2* __restrict__ csr_ed,
        const float* __restrict__ Ux, const float* __restrict__ Vx,
        float* __restrict__ xnew, int n)
{
    int wid = (blockIdx.x * blockDim.x + threadIdx.x) >> 6;
    int lane = threadIdx.x & 63;
    if (wid >= n) return;
    int beg = row_start[wid];
    int end = row_start[wid + 1];
    float m = -INFINITY, s = 0.f, y = 0.f;

    int p = beg;
    while (p + 8 <= end) {
        int2 ed[8];
#pragma unroll
        for (int u = 0; u < 8; ++u) ed[u] = csr_ed[p + u];
        float v[8], vv[8];
#pragma unroll
        for (int u = 0; u < 8; ++u) {
            v[u]  = ehat[(size_t)ed[u].x * 64 + lane];
            vv[u] = Vx[(size_t)ed[u].y * 64 + lane];
        }
#pragma unroll
        for (int u = 0; u < 8; ++u) {
            float mn = fmaxf(m, v[u]);
            float c  = __expf(m - mn);
            float pw = __expf(v[u] - mn);
            s = s * c + pw;
            y = y * c + pw * vv[u];
            m = mn;
        }
        p += 8;
    }
    int cnt = end - p;
    if (cnt > 0) {
        int2 ed[8];
        float v[8], vv[8];
#pragma unroll
        for (int u = 0; u < 8; ++u) {
            int q = p + (u < cnt ? u : 0);
            ed[u] = csr_ed[q];
        }
#pragma unroll
        for (int u = 0; u < 8; ++u) {
            v[u]  = ehat[(size_t)ed[u].x * 64 + lane];
            vv[u] = Vx[(size_t)ed[u].y * 64 + lane];
        }
#pragma unroll
        for (int u = 0; u < 8; ++u) {
            if (u < cnt) {
                float mn = fmaxf(m, v[u]);
                float c  = __expf(m - mn);
                float pw = __expf(v[u] - mn);
                s = s * c + pw;
                y = y * c + pw * vv[u];
                m = mn;
            }
        }
    }

    float agg = (s > 0.f) ? y / s : 0.f;
    int o = wid * LANES + lane;
    xnew[o] = x[o] + leaky(Ux[o] + agg);
}

// ---------------------------------------------------------------------------
// e_new = e_hat + leaky(Ax[src] + Bx[dst] + e_hat@C^T + Cb)
// 16 edges/wave, 4 waves/block. A-frags straight from global (fp32 kept in
// regs as the residual); acc transposed through a small LDS scratch.
// ---------------------------------------------------------------------------
__global__ __launch_bounds__(256) void edge_new_mfma(
        const float* __restrict__ ehat,
        const int* __restrict__ src, const int* __restrict__ dst,
        const float* __restrict__ Ax, const float* __restrict__ Bx,
        const unsigned short* __restrict__ Cbf, const float* __restrict__ Cb,
        float* __restrict__ enew, int e)
{
    __shared__ __align__(16) float sacc[4][16][68];
    int t = threadIdx.x;
    int w = t >> 6, l = t & 63;
    int lo = l & 15, hi = l >> 4;
    long base = ((long)blockIdx.x * 4 + w) * 16;
    long rowA = base + lo;                 // the edge row this lane loads AND finishes
    long rac = rowA < e ? rowA : (long)e - 1;

    // A-frags directly from global; keep fp32 in regs for the residual
    float4 ra[2][2];
    bf16x8 a[2];
#pragma unroll
    for (int s = 0; s < 2; ++s) {
        const float* p = ehat + rac * 64 + s * 32 + hi * 8;
        ra[s][0] = *(const float4*)p;
        ra[s][1] = *(const float4*)(p + 4);
        a[s] = pack8(ra[s][0], ra[s][1]);
    }

    bf16x8 bf[4][2];
    load_bfrags_bf16(Cbf, lo, hi, bf);

    float4 cb[2][2];
#pragma unroll
    for (int s = 0; s < 2; ++s) {
        cb[s][0] = *(const float4*)(Cb + s * 32 + hi * 8);
        cb[s][1] = *(const float4*)(Cb + s * 32 + hi * 8 + 4);
    }

    f32x4 acc[4];
#pragma unroll
    for (int ct = 0; ct < 4; ++ct) {
        acc[ct] = (f32x4){0.f, 0.f, 0.f, 0.f};
        acc[ct] = __builtin_amdgcn_mfma_f32_16x16x32_bf16(a[0], bf[ct][0], acc[ct], 0, 0, 0);
        acc[ct] = __builtin_amdgcn_mfma_f32_16x16x32_bf16(a[1], bf[ct][1], acc[ct], 0, 0, 0);
    }

    // transpose acc through LDS: D[row=hi*4+i][col=ct*16+lo]
#pragma unroll
    for (int ct = 0; ct < 4; ++ct)
#pragma unroll
        for (int i = 0; i < 4; ++i)
            sacc[w][hi * 4 + i][ct * 16 + lo] = acc[ct][i];
    __syncthreads();

    // epilogue: lane finishes row rowA, cols s*32+hi*8 .. +7 (matches ra regs)
    int sn = src[rac], dn = dst[rac];
    const float* ap = Ax + (size_t)sn * 64;
    const float* bp = Bx + (size_t)dn * 64;
#pragma unroll
    for (int s = 0; s < 2; ++s) {
        int c0 = s * 32 + hi * 8;
        float4 av0 = *(const float4*)(ap + c0);
        float4 av1 = *(const float4*)(ap + c0 + 4);
        float4 bv0 = *(const float4*)(bp + c0);
        float4 bv1 = *(const float4*)(bp + c0 + 4);
        float4 ac0 = *(const float4*)&sacc[w][lo][c0];
        float4 ac1 = *(const float4*)&sacc[w][lo][c0 + 4];
        float4 o0 = fuse4(ra[s][0], ac0, av0, bv0, cb[s][0]);
        float4 o1 = fuse4(ra[s][1], ac1, av1, bv1, cb[s][1]);
        if (rowA < e) {
            *(float4*)(enew + rowA * 64 + c0)     = o0;
            *(float4*)(enew + rowA * 64 + c0 + 4) = o1;
        }
    }
}

// ---------------------------------------------------------------------------
extern "C" void kernel_launch(void* const* d_in, const int* in_sizes, int n_in,
                              void* d_out, int out_size, void* d_ws, size_t ws_size,
                              hipStream_t stream)
{
    const float* x    = (const float*)d_in[0];
    const float* ehat = (const float*)d_in[1];
    const int*   ei   = (const int*)d_in[2];
    const float* Uw = (const float*)d_in[3];
    const float* Ub = (const float*)d_in[4];
    const float* Vw = (const float*)d_in[5];
    const float* Vb = (const float*)d_in[6];
    const float* Aw = (const float*)d_in[7];
    const float* Ab = (const float*)d_in[8];
    const float* Bw = (const float*)d_in[9];
    const float* Bb = (const float*)d_in[10];
    const float* Cw = (const float*)d_in[11];
    const float* Cb = (const float*)d_in[12];

    int n = in_sizes[0] / LANES;   // 100000
    int e = in_sizes[1] / LANES;   // 1600000
    const int* src = ei;
    const int* dst = ei + e;

    auto align = [](size_t v) { return (v + 255) & ~(size_t)255; };
    char* w = (char*)d_ws;
    int*  deg    = (int*)w;  w += align((size_t)n * 4);
    int*  cursor = (int*)w;  w += align((size_t)n * 4);
    int*  rs     = (int*)w;  w += align((size_t)(n + 1) * 4);
    int2* csr_ed = (int2*)w; w += align((size_t)e * 8);
    float* Ux    = (float*)w; w += align((size_t)n * LANES * 4);
    float* Vx    = (float*)w; w += align((size_t)n * LANES * 4);
    float* Ax    = (float*)w; w += align((size_t)n * LANES * 4);
    float* Bx    = (float*)w; w += align((size_t)n * LANES * 4);
    unsigned short* Wbf = (unsigned short*)w; w += align((size_t)5 * 4096 * 2);

    float* xnew = (float*)d_out;
    float* enew = xnew + (size_t)n * LANES;

    hipMemsetAsync(deg, 0, (size_t)n * 4, stream);

    cvt_weights<<<80, 256, 0, stream>>>(Uw, Vw, Aw, Bw, Cw, Wbf);

    node_gemm_mfma<<<(n + 63) / 64, 256, 0, stream>>>(x, Wbf, Ub, Vb, Ab, Bb,
                                                      Ux, Vx, Ax, Bx, n);

    hist_kernel<<<(e + 255) / 256, 256, 0, stream>>>(src, deg, e);
    scan_kernel<<<1, 1024, 0, stream>>>(deg, rs, cursor, n);
    fill_kernel<<<(e + 255) / 256, 256, 0, stream>>>(src, dst, cursor, csr_ed, e);

    node_agg<<<(n + 3) / 4, 256, 0, stream>>>(x, ehat, rs, csr_ed, Ux, Vx, xnew, n);

    edge_new_mfma<<<(e + 63) / 64, 256, 0, stream>>>(ehat, src, dst, Ax, Bx,
                                                     Wbf + 4 * 4096, Cb, enew, e);
}